// Round 2
// baseline (300.415 us; speedup 1.0000x reference)
//
#include <hip/hip_runtime.h>
#include <cfloat>

// Problem constants (fixed by setup_inputs)
#define BATCH   32
#define C_DIM   256
#define HW      1024          // 32*32
#define N_ROWS  32768         // BATCH*HW
#define K_CODES 1024
#define ROWS    64            // rows per workgroup
#define ZSTRIDE 260           // padded LDS stride (floats); rows 16B-aligned

#define OUT_ELEMS   8388608   // 32*256*32*32
#define LOSS_OFF    8388608
#define IDX_OFF     8388611

__device__ __forceinline__ bool lessfi(float a, int ia, float b, int ib) {
    return (a < b) || (a == b && ia < ib);
}

// Kernel 1: codebook squared norms — fp64 accumulate, rounded to fp32.
__global__ void enorm_kernel(const float* __restrict__ cb, float* __restrict__ enorm) {
    int k = blockIdx.x * 4 + (threadIdx.x >> 6);
    int lane = threadIdx.x & 63;
    float4 v = *(const float4*)(cb + k * C_DIM + lane * 4);
    double s = (double)v.x * v.x + (double)v.y * v.y + (double)v.z * v.z + (double)v.w * v.w;
    #pragma unroll
    for (int m = 1; m < 64; m <<= 1) s += __shfl_xor(s, m, 64);
    if (lane == 0) enorm[k] = (float)s;
}

// Kernel 2: main VQ — fp32 top-2 prune + fp64 rescore + fp32-reference simulation
__global__ __launch_bounds__(256) void vq_main(const float* __restrict__ x,
                                               const float* __restrict__ cb,
                                               const float* __restrict__ enorm,
                                               float* __restrict__ out,
                                               float* __restrict__ idx_out,
                                               double* __restrict__ dmin_out) {
    __shared__ __align__(16) float zt[ROWS][ZSTRIDE];
    __shared__ float  wq_s1[4][ROWS], wq_s2[4][ROWS];
    __shared__ int    wq_i1[4][ROWS], wq_i2[4][ROWS];
    __shared__ double Srow64[ROWS];
    __shared__ float  Srow32[ROWS];
    __shared__ int    cand[2][ROWS];
    __shared__ float  scand[2][ROWS];
    __shared__ double dcand[2][ROWS];
    __shared__ int    finalidx[ROWS];

    const int t    = threadIdx.x;
    const int row0 = blockIdx.x * ROWS;
    const int b    = row0 >> 10;       // 1024 rows per batch image
    const int hw0  = row0 & 1023;
    const float* xb = x + b * (C_DIM * HW) + hw0;

    // ---- stage z tile: z[row][c] = x[b][c][hw] ----
    {
        int rr4 = (t & 15) * 4;        // 4 consecutive rows (consecutive hw)
        int c0  = t >> 4;              // 0..15
        for (int c = c0; c < C_DIM; c += 16) {
            float4 v = *(const float4*)(xb + c * HW + rr4);
            zt[rr4 + 0][c] = v.x;
            zt[rr4 + 1][c] = v.y;
            zt[rr4 + 2][c] = v.z;
            zt[rr4 + 3][c] = v.w;
        }
    }
    __syncthreads();

    // ---- per-row S = sum z^2 in fp64; S32 = fl32(S) ----
    {
        int r = t >> 2, seg = t & 3;
        const float* zr = &zt[r][seg * 64];
        double s = 0.0;
        for (int c = 0; c < 64; c++) { double z = zr[c]; s = fma(z, z, s); }
        s += __shfl_xor(s, 1, 64);
        s += __shfl_xor(s, 2, 64);
        if (seg == 0) { Srow64[r] = s; Srow32[r] = (float)s; }
    }

    // ---- fp32 pruning pass: s = ||e||^2 - 2 z.e  (row-constant ||z||^2 dropped) ----
    // kq = t>>4: wave-uniform-ish code groups (broadcast-friendly e loads)
    // rows rq + 16*i: 2-way-free LDS bank pattern at ZSTRIDE=260
    const int rq = t & 15;
    const int kq = t >> 4;             // 0..15, 8 codes each -> 128 codes per kt step
    float s1[4], s2[4];
    int   i1[4], i2[4];
    #pragma unroll
    for (int i = 0; i < 4; i++) { s1[i] = FLT_MAX; s2[i] = FLT_MAX; i1[i] = 0x7fffffff; i2[i] = 0x7fffffff; }

    for (int kt = 0; kt < K_CODES; kt += 128) {
        const int kbase = kt + kq * 8;
        const float* e0 = cb + kbase * C_DIM;
        float dot[4][8];
        #pragma unroll
        for (int i = 0; i < 4; i++)
            #pragma unroll
            for (int j = 0; j < 8; j++) dot[i][j] = 0.f;

        for (int c = 0; c < C_DIM; c += 4) {
            float4 zv[4], ev[8];
            #pragma unroll
            for (int i = 0; i < 4; i++) zv[i] = *(const float4*)(&zt[rq + 16 * i][c]);
            #pragma unroll
            for (int j = 0; j < 8; j++) ev[j] = *(const float4*)(e0 + j * C_DIM + c);
            #pragma unroll
            for (int i = 0; i < 4; i++)
                #pragma unroll
                for (int j = 0; j < 8; j++)
                    dot[i][j] = fmaf(zv[i].x, ev[j].x,
                                fmaf(zv[i].y, ev[j].y,
                                fmaf(zv[i].z, ev[j].z,
                                fmaf(zv[i].w, ev[j].w, dot[i][j]))));
        }

        #pragma unroll
        for (int j = 0; j < 8; j++) {
            const int k = kbase + j;
            const float en = enorm[k];
            #pragma unroll
            for (int i = 0; i < 4; i++) {
                float s = fmaf(-2.f, dot[i][j], en);
                if (s < s2[i]) {                       // early-out; scan k ascending
                    if (s < s1[i]) { s2[i] = s1[i]; i2[i] = i1[i]; s1[i] = s; i1[i] = k; }
                    else           { s2[i] = s; i2[i] = k; }
                }
            }
        }
    }

    // ---- within-wave merge across the 4 kq-subgroups (xor 16, 32) ----
    const int lane = t & 63;
    const int wv   = t >> 6;           // wave id 0..3
    #pragma unroll
    for (int m = 16; m <= 32; m <<= 1) {
        #pragma unroll
        for (int i = 0; i < 4; i++) {
            float os1 = __shfl_xor(s1[i], m, 64);
            int   oi1 = __shfl_xor(i1[i], m, 64);
            float os2 = __shfl_xor(s2[i], m, 64);
            int   oi2 = __shfl_xor(i2[i], m, 64);
            if (lessfi(os1, oi1, s1[i], i1[i])) {
                float ns2; int ni2;
                if (lessfi(s1[i], i1[i], os2, oi2)) { ns2 = s1[i]; ni2 = i1[i]; }
                else                                { ns2 = os2;   ni2 = oi2; }
                s1[i] = os1; i1[i] = oi1;
                s2[i] = ns2; i2[i] = ni2;
            } else if (lessfi(os1, oi1, s2[i], i2[i])) {
                s2[i] = os1; i2[i] = oi1;
            }
        }
    }
    if ((lane >> 4) == 0) {            // one lane per (wave, row-slot)
        #pragma unroll
        for (int i = 0; i < 4; i++) {
            int r = rq + 16 * i;
            wq_s1[wv][r] = s1[i]; wq_i1[wv][r] = i1[i];
            wq_s2[wv][r] = s2[i]; wq_i2[wv][r] = i2[i];
        }
    }
    __syncthreads();

    // ---- final top-2 merge across the 4 waves ----
    if (t < ROWS) {
        float b1 = wq_s1[0][t], b2 = wq_s2[0][t];
        int   j1 = wq_i1[0][t], j2 = wq_i2[0][t];
        #pragma unroll
        for (int w = 1; w < 4; w++) {
            float a1 = wq_s1[w][t], a2 = wq_s2[w][t];
            int   c1 = wq_i1[w][t], c2 = wq_i2[w][t];
            if (lessfi(a1, c1, b1, j1)) {
                if (lessfi(b1, j1, a2, c2)) { b2 = b1; j2 = j1; }
                else                        { b2 = a2; j2 = c2; }
                b1 = a1; j1 = c1;
            } else if (lessfi(a1, c1, b2, j2)) {
                b2 = a1; j2 = c1;
            }
        }
        cand[0][t] = j1;
        cand[1][t] = j2;
    }
    __syncthreads();

    // ---- rescore both candidates: fp64 dot, then simulate the fp32 reference:
    //      t2 = fl32( fl32(S32 - fl32(2*Mf)) + E32 )   (numpy's op order)   ----
    {
        int task = t >> 1;             // 128 tasks: row x candidate
        int hf   = t & 1;              // half of C
        int r    = task & 63;
        int ci   = task >> 6;
        int id   = cand[ci][r];
        const float* e  = cb + id * C_DIM + hf * 128;
        const float* zr = &zt[r][hf * 128];
        double dot = 0.0;
        for (int c = 0; c < 128; c++) dot = fma((double)zr[c], (double)e[c], dot);
        dot += __shfl_xor(dot, 1, 64);
        if (hf == 0) {
            float Mf = (float)dot;                       // sgemm-result estimate, fp32
            float M2 = __fmul_rn(2.0f, Mf);              // exact
            float t1 = __fsub_rn(Srow32[r], M2);         // fp32 rounding #1
            float t2 = __fadd_rn(t1, enorm[id]);         // fp32 rounding #2
            scand[ci][r] = t2;
            dcand[ci][r] = Srow64[r] - 2.0 * dot + (double)enorm[id];  // for losses
        }
    }
    __syncthreads();

    if (t < ROWS) {
        float f0 = scand[0][t], f1 = scand[1][t];
        int  id0 = cand[0][t],  id1 = cand[1][t];
        int fid; double db;
        if (lessfi(f1, id1, f0, id0)) { fid = id1; db = dcand[1][t]; }
        else                          { fid = id0; db = dcand[0][t]; }
        finalidx[t] = fid;
        dmin_out[row0 + t] = db;
        idx_out[row0 + t] = (float)fid;
    }
    __syncthreads();

    // ---- write quantized output (NCHW), store-coalesced: lanes = rows ----
    {
        int rr = t & 63;
        int cg = t >> 6;               // 0..3 -> 64 channels each
        int fid = finalidx[rr];
        const float* er = cb + fid * C_DIM;
        float* ob = out + b * (C_DIM * HW) + hw0 + rr;
        for (int cc = cg * 64; cc < cg * 64 + 64; cc++) {
            ob[cc * HW] = er[cc];
        }
    }
}

// Kernel 3: deterministic fp64 loss reduction
__global__ void loss_kernel(const double* __restrict__ dmin, float* __restrict__ losses) {
    __shared__ double sh[256];
    int t = threadIdx.x;
    double a = 0.0;
    const int per = N_ROWS / 256;      // 128
    for (int i = t * per; i < t * per + per; i++) a += dmin[i];
    sh[t] = a;
    __syncthreads();
    for (int s = 128; s > 0; s >>= 1) {
        if (t < s) sh[t] += sh[t + s];
        __syncthreads();
    }
    if (t == 0) {
        double M = sh[0] / (double)OUT_ELEMS;   // mean over B*H*W*C elements
        losses[0] = (float)(1.25 * M);          // quantizer_loss
        losses[1] = (float)(0.25 * M);          // e_latent_loss
        losses[2] = (float)(M);                 // q_latent_loss
    }
}

extern "C" void kernel_launch(void* const* d_in, const int* in_sizes, int n_in,
                              void* d_out, int out_size, void* d_ws, size_t ws_size,
                              hipStream_t stream) {
    const float* x  = (const float*)d_in[0];
    const float* cb = (const float*)d_in[1];
    float* out     = (float*)d_out;
    float* losses  = out + LOSS_OFF;
    float* idx_out = out + IDX_OFF;

    double* dmin  = (double*)d_ws;                                    // 32768 doubles
    float*  enorm = (float*)((char*)d_ws + N_ROWS * sizeof(double));  // 1024 floats

    enorm_kernel<<<K_CODES / 4, 256, 0, stream>>>(cb, enorm);
    vq_main<<<N_ROWS / ROWS, 256, 0, stream>>>(x, cb, enorm, out, idx_out, dmin);
    loss_kernel<<<1, 256, 0, stream>>>(dmin, losses);
}

// Round 3
// 191.999 us; speedup vs baseline: 1.5647x; 1.5647x over previous
//
#include <hip/hip_runtime.h>
#include <cfloat>

// Problem constants (fixed by setup_inputs)
#define C_DIM   256
#define HW      1024
#define N_ROWS  32768
#define K_CODES 1024
#define ROWS    64            // rows per workgroup
#define ZSTRIDE 260           // padded LDS stride (floats)
#define NCHUNK  16            // 1024 codes / 64 per chunk
#define CHUNK_BYTES 32768     // 64 codes * 256 * 2B fp16
#define LISTCAP 512
#define DELTA_PUSH 0.02f
#define DELTA_FILT 0.008f

#define OUT_ELEMS 8388608
#define LOSS_OFF  8388608
#define IDX_OFF   8388611

typedef _Float16 half8 __attribute__((ext_vector_type(8)));
typedef _Float16 f16x4 __attribute__((ext_vector_type(4)));
typedef float    f32x4 __attribute__((ext_vector_type(4)));

#define AS1 __attribute__((address_space(1)))
#define AS3 __attribute__((address_space(3)))

// dynamic LDS layout (bytes)
#define OFF_ZT    0                    // 64*260*4 = 66560
#define OFF_EBUF  66560                // 2*32768  = 65536
#define OFF_EN    132096               // 1024*4   = 4096
#define OFF_S32   136192               // 64*4     = 256
#define OFF_M1W   136448               // 4*64*4   = 1024
#define OFF_THR   137472               // 64*4     = 256
#define OFF_RES   137728               // 64*8     = 512
#define OFF_FIDX  138240               // 64*4     = 256
#define OFF_LCNT  138496               // 16
#define OFF_LMETA 138512               // 4*512*4  = 8192
#define OFF_LSVAL 146704               // 4*512*4  = 8192
#define SMEM_BYTES 154896

// DPP min across the 16-lane row group (lanes sharing lane>>4)
#define DPP_MIN(x, ctrl) fminf((x), __int_as_float(__builtin_amdgcn_update_dpp(0, __float_as_int(x), (ctrl), 0xf, 0xf, true)))

// Kernel 1: codebook prep — fp32 norms (fp64-accurate) + fp16 copy, pre-swizzled
// ws fp16 layout: byte = (k/64)*32768 + (k%64)*512 + ((c*2) ^ ((k&7)<<4))
__global__ void prep_kernel(const float* __restrict__ cb, float* __restrict__ enorm,
                            char* __restrict__ cb16) {
    int k = blockIdx.x * 4 + (threadIdx.x >> 6);
    int lane = threadIdx.x & 63;
    float4 v = *(const float4*)(cb + k * C_DIM + lane * 4);
    double s = (double)v.x * v.x + (double)v.y * v.y + (double)v.z * v.z + (double)v.w * v.w;
    #pragma unroll
    for (int m = 1; m < 64; m <<= 1) s += __shfl_xor(s, m, 64);
    if (lane == 0) enorm[k] = (float)s;
    f16x4 h;
    h[0] = (_Float16)v.x; h[1] = (_Float16)v.y; h[2] = (_Float16)v.z; h[3] = (_Float16)v.w;
    int dst = ((k >> 6) << 15) + ((k & 63) << 9) + ((lane * 8) ^ ((k & 7) << 4));
    *(f16x4*)(cb16 + dst) = h;
}

// Kernel 2: fp16-MFMA prune (delta-ball capture) + exact fp32-sim rescore
__global__ __launch_bounds__(256, 1) void vq_main(
    const float* __restrict__ x, const float* __restrict__ cb,
    const float* __restrict__ enorm_g, const char* __restrict__ cb16,
    float* __restrict__ out, float* __restrict__ idx_out, float* __restrict__ t2_out)
{
    extern __shared__ char smem[];
    float* zt      = (float*)(smem + OFF_ZT);
    char*  ebuf    = smem + OFF_EBUF;
    float* en_lds  = (float*)(smem + OFF_EN);
    float* S32     = (float*)(smem + OFF_S32);
    float* m1w     = (float*)(smem + OFF_M1W);
    float* thr     = (float*)(smem + OFF_THR);
    unsigned long long* res = (unsigned long long*)(smem + OFF_RES);
    int*   fidx    = (int*)(smem + OFF_FIDX);
    int*   lcnt    = (int*)(smem + OFF_LCNT);
    unsigned int* lmeta = (unsigned int*)(smem + OFF_LMETA);
    float* lsval   = (float*)(smem + OFF_LSVAL);

    const int t    = threadIdx.x;
    const int lane = t & 63;
    const int wv   = t >> 6;
    const int l15  = lane & 15;
    const int l4   = lane >> 4;
    const int row0 = blockIdx.x * ROWS;
    const int b    = row0 >> 10;
    const int hw0  = row0 & 1023;
    const float* xb = x + b * (C_DIM * HW) + hw0;

    // ---- stage z tile (transpose, vectorized 4x4) ----
    {
        int g   = t & 15;      // rows 4g..4g+3
        int cb4 = t >> 4;      // c-block
        for (int cc = cb4 * 4; cc < C_DIM; cc += 64) {
            float4 v0 = *(const float4*)(xb + (cc + 0) * HW + g * 4);
            float4 v1 = *(const float4*)(xb + (cc + 1) * HW + g * 4);
            float4 v2 = *(const float4*)(xb + (cc + 2) * HW + g * 4);
            float4 v3 = *(const float4*)(xb + (cc + 3) * HW + g * 4);
            *(float4*)&zt[(g * 4 + 0) * ZSTRIDE + cc] = make_float4(v0.x, v1.x, v2.x, v3.x);
            *(float4*)&zt[(g * 4 + 1) * ZSTRIDE + cc] = make_float4(v0.y, v1.y, v2.y, v3.y);
            *(float4*)&zt[(g * 4 + 2) * ZSTRIDE + cc] = make_float4(v0.z, v1.z, v2.z, v3.z);
            *(float4*)&zt[(g * 4 + 3) * ZSTRIDE + cc] = make_float4(v0.w, v1.w, v2.w, v3.w);
        }
    }
    // ---- stage enorm ----
    {
        float4 e4 = *(const float4*)(enorm_g + t * 4);
        *(float4*)&en_lds[t * 4] = e4;
    }
    if (t < 4) lcnt[t] = 0;
    // ---- stage e-chunk 0 ----
    {
        const char* src = cb16;
        #pragma unroll
        for (int i = 0; i < 8; i++) {
            int base = wv * 8192 + i * 1024;
            __builtin_amdgcn_global_load_lds((const AS1 unsigned int*)(src + base + lane * 16),
                                             (AS3 unsigned int*)(ebuf + base), 16, 0, 0);
        }
    }
    __syncthreads();

    // ---- per-row S32 = fl32(sum z^2 in fp64) ----
    {
        int r = t >> 2, seg = t & 3;
        const float* zr = &zt[r * ZSTRIDE + seg * 64];
        double s = 0.0;
        for (int c = 0; c < 64; c += 4) {
            float4 v = *(const float4*)(zr + c);
            s = fma((double)v.x, (double)v.x, s);
            s = fma((double)v.y, (double)v.y, s);
            s = fma((double)v.z, (double)v.z, s);
            s = fma((double)v.w, (double)v.w, s);
        }
        s += __shfl_xor(s, 1, 64);
        s += __shfl_xor(s, 2, 64);
        if (seg == 0) S32[r] = (float)s;
    }

    // ---- build A fragments: all 64 rows, fp16, in registers ----
    // A layout: lane row = l15, k = l4*8 + j (+32*kk)
    half8 af[4][8];
    #pragma unroll
    for (int rt = 0; rt < 4; rt++) {
        int row = rt * 16 + l15;
        #pragma unroll
        for (int kk = 0; kk < 8; kk++) {
            int c0 = kk * 32 + l4 * 8;
            float4 a  = *(const float4*)&zt[row * ZSTRIDE + c0];
            float4 a2 = *(const float4*)&zt[row * ZSTRIDE + c0 + 4];
            half8 h;
            h[0] = (_Float16)a.x;  h[1] = (_Float16)a.y;  h[2] = (_Float16)a.z;  h[3] = (_Float16)a.w;
            h[4] = (_Float16)a2.x; h[5] = (_Float16)a2.y; h[6] = (_Float16)a2.z; h[7] = (_Float16)a2.w;
            af[rt][kk] = h;
        }
    }

    float m1v[4][4];
    #pragma unroll
    for (int rt = 0; rt < 4; rt++)
        #pragma unroll
        for (int r2 = 0; r2 < 4; r2++) m1v[rt][r2] = FLT_MAX;

    const int codeL = wv * 16 + l15;            // this lane's code column within chunk
    const int swz   = (codeL & 7) << 4;
    const int ebrow = codeL * 512;

    // ---- main sweep: 16 chunks of 64 codes ----
    for (int ch = 0; ch < NCHUNK; ch++) {
        const char* ebc = ebuf + (ch & 1) * CHUNK_BYTES;
        if (ch + 1 < NCHUNK) {
            char* ebn = ebuf + ((ch + 1) & 1) * CHUNK_BYTES;
            const char* src = cb16 + (ch + 1) * CHUNK_BYTES;
            #pragma unroll
            for (int i = 0; i < 8; i++) {
                int base = wv * 8192 + i * 1024;
                __builtin_amdgcn_global_load_lds((const AS1 unsigned int*)(src + base + lane * 16),
                                                 (AS3 unsigned int*)(ebn + base), 16, 0, 0);
            }
        }
        f32x4 acc[4];
        #pragma unroll
        for (int rt = 0; rt < 4; rt++) { f32x4 z = {0.f, 0.f, 0.f, 0.f}; acc[rt] = z; }
        #pragma unroll
        for (int kk = 0; kk < 8; kk++) {
            half8 bf = *(const half8*)(ebc + ebrow + (((kk << 6) | (l4 << 4)) ^ swz));
            #pragma unroll
            for (int rt = 0; rt < 4; rt++)
                acc[rt] = __builtin_amdgcn_mfma_f32_16x16x32_f16(af[rt][kk], bf, acc[rt], 0, 0, 0);
        }
        const int codeG = ch * 64 + codeL;
        const float en = en_lds[codeG];
        #pragma unroll
        for (int rt = 0; rt < 4; rt++) {
            #pragma unroll
            for (int r2 = 0; r2 < 4; r2++) {
                float s = fmaf(-2.f, acc[rt][r2], en);
                float m = s;
                m = DPP_MIN(m, 0xB1);    // quad xor1
                m = DPP_MIN(m, 0x4E);    // quad xor2
                m = DPP_MIN(m, 0x141);   // row_half_mirror
                m = DPP_MIN(m, 0x140);   // row_mirror -> min over 16-lane row group
                float base = (ch == 0) ? m : m1v[rt][r2];
                bool hit = s < base + DELTA_PUSH;
                m1v[rt][r2] = fminf(m1v[rt][r2], m);
                if (hit) {
                    int slot = atomicAdd(&lcnt[wv], 1);
                    if (slot < LISTCAP) {
                        int row = rt * 16 + l4 * 4 + r2;
                        lmeta[wv * LISTCAP + slot] = ((unsigned)row << 16) | (unsigned)codeG;
                        lsval[wv * LISTCAP + slot] = s;
                    }
                }
            }
        }
        __syncthreads();
    }

    // ---- global per-row prune-min ----
    if (l15 == 0) {
        #pragma unroll
        for (int rt = 0; rt < 4; rt++)
            #pragma unroll
            for (int r2 = 0; r2 < 4; r2++)
                m1w[wv * 64 + rt * 16 + l4 * 4 + r2] = m1v[rt][r2];
    }
    __syncthreads();
    if (t < 64) {
        float mm = fminf(fminf(m1w[t], m1w[64 + t]), fminf(m1w[128 + t], m1w[192 + t]));
        thr[t] = mm + DELTA_FILT;
        res[t] = ~0ull;
    }
    __syncthreads();

    // ---- rescore survivors: fp64 dot -> fp32 reference simulation ----
    {
        int n = lcnt[wv]; if (n > LISTCAP) n = LISTCAP;
        for (int it = 0; it < n; ++it) {
            unsigned meta = lmeta[wv * LISTCAP + it];
            float sv = lsval[wv * LISTCAP + it];
            int row  = (int)(meta >> 16);
            int code = (int)(meta & 0xffffu);
            if (sv > thr[row]) continue;
            float4 zv = *(const float4*)&zt[row * ZSTRIDE + lane * 4];
            float4 ev = *(const float4*)&cb[code * C_DIM + lane * 4];
            double d = (double)zv.x * (double)ev.x;
            d = fma((double)zv.y, (double)ev.y, d);
            d = fma((double)zv.z, (double)ev.z, d);
            d = fma((double)zv.w, (double)ev.w, d);
            #pragma unroll
            for (int mm2 = 1; mm2 < 64; mm2 <<= 1) d += __shfl_xor(d, mm2, 64);
            if (lane == 0) {
                float Mf = (float)d;
                float t2 = __fadd_rn(__fsub_rn(S32[row], __fmul_rn(2.0f, Mf)), en_lds[code]);
                unsigned long long pk =
                    ((unsigned long long)__float_as_uint(t2) << 32) | (unsigned long long)(unsigned)code;
                atomicMin(&res[row], pk);
            }
        }
    }
    __syncthreads();

    if (t < 64) {
        unsigned long long v = res[t];
        int code = (int)(v & 0xffffu) & 1023;
        fidx[t] = code;
        idx_out[row0 + t] = (float)code;
        t2_out[row0 + t] = __uint_as_float((unsigned)(v >> 32));
    }
    __syncthreads();

    // ---- quantized output (NCHW), store-coalesced ----
    {
        int rr = t & 63;
        int cg = t >> 6;
        int code = fidx[rr];
        const float* er = cb + code * C_DIM;
        float* ob = out + b * (C_DIM * HW) + hw0 + rr;
        for (int cc = cg * 64; cc < cg * 64 + 64; cc++) ob[cc * HW] = er[cc];
    }
}

// Kernel 3: deterministic loss reduction over per-row t2
__global__ void loss_kernel(const float* __restrict__ t2min, float* __restrict__ losses) {
    __shared__ double sh[256];
    int t = threadIdx.x;
    double a = 0.0;
    const int per = N_ROWS / 256;
    for (int i = t * per; i < t * per + per; i++) a += (double)t2min[i];
    sh[t] = a;
    __syncthreads();
    for (int s = 128; s > 0; s >>= 1) {
        if (t < s) sh[t] += sh[t + s];
        __syncthreads();
    }
    if (t == 0) {
        double M = sh[0] / (double)OUT_ELEMS;
        losses[0] = (float)(1.25 * M);   // quantizer_loss
        losses[1] = (float)(0.25 * M);   // e_latent_loss
        losses[2] = (float)(M);          // q_latent_loss
    }
}

extern "C" void kernel_launch(void* const* d_in, const int* in_sizes, int n_in,
                              void* d_out, int out_size, void* d_ws, size_t ws_size,
                              hipStream_t stream) {
    const float* x  = (const float*)d_in[0];
    const float* cb = (const float*)d_in[1];
    float* out     = (float*)d_out;
    float* losses  = out + LOSS_OFF;
    float* idx_out = out + IDX_OFF;

    char*  cb16     = (char*)d_ws;                               // 524288 B
    float* t2ws     = (float*)((char*)d_ws + 524288);            // 131072 B
    float* enorm_ws = (float*)((char*)d_ws + 524288 + 131072);   // 4096 B

    hipFuncSetAttribute(reinterpret_cast<const void*>(vq_main),
                        hipFuncAttributeMaxDynamicSharedMemorySize, SMEM_BYTES);

    prep_kernel<<<K_CODES / 4, 256, 0, stream>>>(cb, enorm_ws, cb16);
    vq_main<<<N_ROWS / ROWS, 256, SMEM_BYTES, stream>>>(x, cb, enorm_ws, cb16, out, idx_out, t2ws);
    loss_kernel<<<1, 256, 0, stream>>>(t2ws, losses);
}

// Round 4
// 104.322 us; speedup vs baseline: 2.8797x; 1.8404x over previous
//
#include <hip/hip_runtime.h>
#include <cfloat>

// Problem constants (fixed by setup_inputs)
#define C_DIM   256
#define HW      1024
#define N_ROWS  32768
#define K_CODES 1024
#define ROWS    64            // rows per workgroup
#define ZSTRIDE 260           // padded LDS stride (floats) for the phase-1 z tile
#define NCHUNK  16            // 1024 codes / 64 per chunk
#define CHUNK_BYTES 32768     // 64 codes * 256 * 2B fp16
#define LISTCAP 256           // per-wave candidate list
#define DELTA_PUSH 0.02f
#define DELTA_FILT 0.008f

#define OUT_ELEMS 8388608
#define LOSS_OFF  8388608
#define IDX_OFF   8388611

typedef _Float16 half8 __attribute__((ext_vector_type(8)));
typedef _Float16 f16x4 __attribute__((ext_vector_type(4)));
typedef float    f32x4 __attribute__((ext_vector_type(4)));

#define AS1 __attribute__((address_space(1)))
#define AS3 __attribute__((address_space(3)))

// dynamic LDS layout (bytes) — zt [64][260] fp32 (66560B) ALIASES [0,66560):
// it is only live before the sweep; ebuf chunks overwrite it afterwards.
#define OFF_EBUF  0                    // 2*32768 = 65536
#define OFF_EN    66560                // 1024*4  = 4096   (clear of zt)
#define OFF_S32   70656                // 64*4
#define OFF_M1W   70912                // 2*64*4
#define OFF_THR   71424                // 64*4
#define OFF_RES   71680                // 64*8
#define OFF_FIDX  72192                // 64*4
#define OFF_LCNT  72448                // 64
#define OFF_LMETA 72512                // 4*256*4
#define OFF_LSVAL 76608                // 4*256*4
#define SMEM_BYTES 80704               // <= 81920 -> 2 blocks/CU

// min across the 16-lane row group
#define DPP_MIN(x, ctrl) fminf((x), __int_as_float(__builtin_amdgcn_update_dpp(0, __float_as_int(x), (ctrl), 0xf, 0xf, true)))

// Kernel 1: codebook prep — fp32 norms (fp64-accurate) + fp16 copy, pre-swizzled
// ws fp16 layout: byte = (k/64)*32768 + (k%64)*512 + ((c*2) ^ ((k&7)<<4))
__global__ void prep_kernel(const float* __restrict__ cb, float* __restrict__ enorm,
                            char* __restrict__ cb16) {
    int k = blockIdx.x * 4 + (threadIdx.x >> 6);
    int lane = threadIdx.x & 63;
    float4 v = *(const float4*)(cb + k * C_DIM + lane * 4);
    double s = (double)v.x * v.x + (double)v.y * v.y + (double)v.z * v.z + (double)v.w * v.w;
    #pragma unroll
    for (int m = 1; m < 64; m <<= 1) s += __shfl_xor(s, m, 64);
    if (lane == 0) enorm[k] = (float)s;
    f16x4 h;
    h[0] = (_Float16)v.x; h[1] = (_Float16)v.y; h[2] = (_Float16)v.z; h[3] = (_Float16)v.w;
    int dst = ((k >> 6) << 15) + ((k & 63) << 9) + ((lane * 8) ^ ((k & 7) << 4));
    *(f16x4*)(cb16 + dst) = h;
}

// Kernel 2: fp16-MFMA prune (delta-ball capture) + exact fp32-sim rescore
__global__ __launch_bounds__(256, 2) void vq_main(
    const float* __restrict__ x, const float* __restrict__ cb,
    const float* __restrict__ enorm_g, const char* __restrict__ cb16,
    float* __restrict__ out, float* __restrict__ idx_out, float* __restrict__ t2_out)
{
    extern __shared__ char smem[];
    char*  ebuf    = smem + OFF_EBUF;
    float* zt      = (float*)(smem + OFF_EBUF);       // alias, phase-1 only
    float* en_lds  = (float*)(smem + OFF_EN);
    float* S32     = (float*)(smem + OFF_S32);
    float* m1w     = (float*)(smem + OFF_M1W);
    float* thr     = (float*)(smem + OFF_THR);
    unsigned long long* res = (unsigned long long*)(smem + OFF_RES);
    int*   fidx    = (int*)(smem + OFF_FIDX);
    int*   lcnt    = (int*)(smem + OFF_LCNT);
    unsigned int* lmeta = (unsigned int*)(smem + OFF_LMETA);
    float* lsval   = (float*)(smem + OFF_LSVAL);

    const int t    = threadIdx.x;
    const int lane = t & 63;
    const int wv   = t >> 6;
    const int wr   = wv >> 1;          // row half: rows wr*32 .. wr*32+31
    const int wc   = wv & 1;           // code half within chunk
    const int l15  = lane & 15;
    const int l4   = lane >> 4;
    const int row0 = blockIdx.x * ROWS;
    const int b    = row0 >> 10;
    const int hw0  = row0 & 1023;
    const float* xb = x + b * (C_DIM * HW) + hw0;

    // ---- phase 1: stage z tile (transpose, vectorized 4x4) + enorm ----
    {
        int g   = t & 15;      // rows 4g..4g+3
        int cb4 = t >> 4;      // c-block
        for (int cc = cb4 * 4; cc < C_DIM; cc += 64) {
            float4 v0 = *(const float4*)(xb + (cc + 0) * HW + g * 4);
            float4 v1 = *(const float4*)(xb + (cc + 1) * HW + g * 4);
            float4 v2 = *(const float4*)(xb + (cc + 2) * HW + g * 4);
            float4 v3 = *(const float4*)(xb + (cc + 3) * HW + g * 4);
            *(float4*)&zt[(g * 4 + 0) * ZSTRIDE + cc] = make_float4(v0.x, v1.x, v2.x, v3.x);
            *(float4*)&zt[(g * 4 + 1) * ZSTRIDE + cc] = make_float4(v0.y, v1.y, v2.y, v3.y);
            *(float4*)&zt[(g * 4 + 2) * ZSTRIDE + cc] = make_float4(v0.z, v1.z, v2.z, v3.z);
            *(float4*)&zt[(g * 4 + 3) * ZSTRIDE + cc] = make_float4(v0.w, v1.w, v2.w, v3.w);
        }
        float4 e4 = *(const float4*)(enorm_g + t * 4);
        *(float4*)&en_lds[t * 4] = e4;
        if (t < 4) lcnt[t] = 0;
    }
    __syncthreads();

    // ---- phase 2: S32 + A fragments (reads zt; zt dies after this) ----
    {
        int r = t >> 2, seg = t & 3;
        const float* zr = &zt[r * ZSTRIDE + seg * 64];
        double s = 0.0;
        for (int c = 0; c < 64; c += 4) {
            float4 v = *(const float4*)(zr + c);
            s = fma((double)v.x, (double)v.x, s);
            s = fma((double)v.y, (double)v.y, s);
            s = fma((double)v.z, (double)v.z, s);
            s = fma((double)v.w, (double)v.w, s);
        }
        s += __shfl_xor(s, 1, 64);
        s += __shfl_xor(s, 2, 64);
        if (seg == 0) S32[r] = (float)s;
    }

    half8 af[2][8];                    // 32 rows of this wave, fp16, 64 VGPRs
    #pragma unroll
    for (int rt = 0; rt < 2; rt++) {
        int row = wr * 32 + rt * 16 + l15;
        #pragma unroll
        for (int kk = 0; kk < 8; kk++) {
            int c0 = kk * 32 + l4 * 8;
            float4 a  = *(const float4*)&zt[row * ZSTRIDE + c0];
            float4 a2 = *(const float4*)&zt[row * ZSTRIDE + c0 + 4];
            half8 h;
            h[0] = (_Float16)a.x;  h[1] = (_Float16)a.y;  h[2] = (_Float16)a.z;  h[3] = (_Float16)a.w;
            h[4] = (_Float16)a2.x; h[5] = (_Float16)a2.y; h[6] = (_Float16)a2.z; h[7] = (_Float16)a2.w;
            af[rt][kk] = h;
        }
    }
    __syncthreads();                   // zt dead; ebuf may now overwrite it

    // ---- stage chunk 0 ----
    #pragma unroll
    for (int i = 0; i < 8; i++) {
        int base = wv * 8192 + i * 1024;
        __builtin_amdgcn_global_load_lds((const AS1 unsigned int*)(cb16 + base + lane * 16),
                                         (AS3 unsigned int*)(ebuf + base), 16, 0, 0);
    }
    __syncthreads();

    const int codeL = wc * 32 + l15;   // base code column (nt adds 16)
    const int swz   = (l15 & 7) << 4;
    float m1v[2][4];

    // ---- main sweep: 16 chunks of 64 codes ----
    for (int ch = 0; ch < NCHUNK; ch++) {
        const char* ebc = ebuf + (ch & 1) * CHUNK_BYTES;
        if (ch + 1 < NCHUNK) {
            char* ebn = ebuf + ((ch + 1) & 1) * CHUNK_BYTES;
            const char* src = cb16 + (ch + 1) * CHUNK_BYTES;
            #pragma unroll
            for (int i = 0; i < 8; i++) {
                int base = wv * 8192 + i * 1024;
                __builtin_amdgcn_global_load_lds((const AS1 unsigned int*)(src + base + lane * 16),
                                                 (AS3 unsigned int*)(ebn + base), 16, 0, 0);
            }
        }
        f32x4 acc[2][2];
        #pragma unroll
        for (int rt = 0; rt < 2; rt++)
            #pragma unroll
            for (int nt = 0; nt < 2; nt++) { f32x4 z = {0.f, 0.f, 0.f, 0.f}; acc[rt][nt] = z; }

        #pragma unroll
        for (int kk = 0; kk < 8; kk++) {
            const int col = ((kk << 6) | (l4 << 4)) ^ swz;
            half8 bf0 = *(const half8*)(ebc + ((codeL     ) << 9) + col);
            half8 bf1 = *(const half8*)(ebc + ((codeL + 16) << 9) + col);
            #pragma unroll
            for (int rt = 0; rt < 2; rt++) {
                acc[rt][0] = __builtin_amdgcn_mfma_f32_16x16x32_f16(af[rt][kk], bf0, acc[rt][0], 0, 0, 0);
                acc[rt][1] = __builtin_amdgcn_mfma_f32_16x16x32_f16(af[rt][kk], bf1, acc[rt][1], 0, 0, 0);
            }
        }

        const int code0 = ch * 64 + wc * 32 + l15;
        const float en0 = en_lds[code0];
        const float en1 = en_lds[code0 + 16];
        #pragma unroll
        for (int rt = 0; rt < 2; rt++) {
            #pragma unroll
            for (int r2 = 0; r2 < 4; r2++) {
                float s0 = fmaf(-2.f, acc[rt][0][r2], en0);
                float s1 = fmaf(-2.f, acc[rt][1][r2], en1);
                float m = fminf(s0, s1);
                m = DPP_MIN(m, 0xB1);
                m = DPP_MIN(m, 0x4E);
                m = DPP_MIN(m, 0x141);
                m = DPP_MIN(m, 0x140);   // min over 16-lane group = min over 32 codes
                float base = (ch == 0) ? m : m1v[rt][r2];
                float limit = base + DELTA_PUSH;
                m1v[rt][r2] = (ch == 0) ? m : fminf(m1v[rt][r2], m);
                int row_l = wr * 32 + rt * 16 + l4 * 4 + r2;
                if (s0 < limit) {
                    int slot = atomicAdd(&lcnt[wv], 1);
                    if (slot < LISTCAP) {
                        lmeta[wv * LISTCAP + slot] = ((unsigned)row_l << 16) | (unsigned)code0;
                        lsval[wv * LISTCAP + slot] = s0;
                    }
                }
                if (s1 < limit) {
                    int slot = atomicAdd(&lcnt[wv], 1);
                    if (slot < LISTCAP) {
                        lmeta[wv * LISTCAP + slot] = ((unsigned)row_l << 16) | (unsigned)(code0 + 16);
                        lsval[wv * LISTCAP + slot] = s1;
                    }
                }
            }
        }
        __syncthreads();
    }

    // ---- global per-row prune-min across the two wc-waves ----
    if (l15 == 0) {
        #pragma unroll
        for (int rt = 0; rt < 2; rt++)
            #pragma unroll
            for (int r2 = 0; r2 < 4; r2++)
                m1w[wc * 64 + wr * 32 + rt * 16 + l4 * 4 + r2] = m1v[rt][r2];
    }
    __syncthreads();
    if (t < 64) {
        thr[t] = fminf(m1w[t], m1w[64 + t]) + DELTA_FILT;
        res[t] = ~0ull;
    }
    __syncthreads();

    // ---- rescore survivors: fp64 dot (z re-read from global) -> fp32 ref sim ----
    {
        int n = lcnt[wv]; if (n > LISTCAP) n = LISTCAP;
        for (int base = 0; base < n; base += 4) {
            int it = base + l4;
            bool act = it < n;
            unsigned meta = act ? lmeta[wv * LISTCAP + it] : 0u;
            float sv = act ? lsval[wv * LISTCAP + it] : FLT_MAX;
            int row  = (int)(meta >> 16);
            int code = (int)(meta & 1023u);
            if (act && sv <= thr[row]) {
                const float* xr = xb + row;            // element c at xr[c*HW]
                const float* er = cb + code * C_DIM;
                double acc = 0.0;
                #pragma unroll
                for (int s2 = 0; s2 < 16; s2++) {
                    int c = l15 + 16 * s2;
                    acc = fma((double)xr[(size_t)c * HW], (double)er[c], acc);
                }
                acc += __shfl_xor(acc, 1, 64);
                acc += __shfl_xor(acc, 2, 64);
                acc += __shfl_xor(acc, 4, 64);
                acc += __shfl_xor(acc, 8, 64);
                if (l15 == 0) {
                    float Mf = (float)acc;
                    float t2 = __fadd_rn(__fsub_rn(S32[row], __fmul_rn(2.0f, Mf)), en_lds[code]);
                    unsigned long long pk =
                        ((unsigned long long)__float_as_uint(t2) << 32) | (unsigned long long)(unsigned)code;
                    atomicMin(&res[row], pk);
                }
            }
        }
    }
    __syncthreads();

    if (t < 64) {
        unsigned long long v = res[t];
        int code = (int)(v & 1023u);
        fidx[t] = code;
        idx_out[row0 + t] = (float)code;
        t2_out[row0 + t] = __uint_as_float((unsigned)(v >> 32));
    }
    __syncthreads();

    // ---- quantized output (NCHW), store-coalesced ----
    {
        int rr = t & 63;
        int cg = t >> 6;
        int code = fidx[rr];
        const float* er = cb + code * C_DIM;
        float* ob = out + b * (C_DIM * HW) + hw0 + rr;
        for (int cc = cg * 64; cc < cg * 64 + 64; cc++) ob[cc * HW] = er[cc];
    }
}

// Kernel 3: deterministic loss reduction over per-row t2
__global__ void loss_kernel(const float* __restrict__ t2min, float* __restrict__ losses) {
    __shared__ double sh[256];
    int t = threadIdx.x;
    double a = 0.0;
    const int per = N_ROWS / 256;
    for (int i = t * per; i < t * per + per; i++) a += (double)t2min[i];
    sh[t] = a;
    __syncthreads();
    for (int s = 128; s > 0; s >>= 1) {
        if (t < s) sh[t] += sh[t + s];
        __syncthreads();
    }
    if (t == 0) {
        double M = sh[0] / (double)OUT_ELEMS;
        losses[0] = (float)(1.25 * M);   // quantizer_loss
        losses[1] = (float)(0.25 * M);   // e_latent_loss
        losses[2] = (float)(M);          // q_latent_loss
    }
}

extern "C" void kernel_launch(void* const* d_in, const int* in_sizes, int n_in,
                              void* d_out, int out_size, void* d_ws, size_t ws_size,
                              hipStream_t stream) {
    const float* x  = (const float*)d_in[0];
    const float* cb = (const float*)d_in[1];
    float* out     = (float*)d_out;
    float* losses  = out + LOSS_OFF;
    float* idx_out = out + IDX_OFF;

    char*  cb16     = (char*)d_ws;                               // 524288 B
    float* t2ws     = (float*)((char*)d_ws + 524288);            // 131072 B
    float* enorm_ws = (float*)((char*)d_ws + 524288 + 131072);   // 4096 B

    hipFuncSetAttribute(reinterpret_cast<const void*>(vq_main),
                        hipFuncAttributeMaxDynamicSharedMemorySize, SMEM_BYTES);

    prep_kernel<<<K_CODES / 4, 256, 0, stream>>>(cb, enorm_ws, cb16);
    vq_main<<<N_ROWS / ROWS, 256, SMEM_BYTES, stream>>>(x, cb, enorm_ws, cb16, out, idx_out, t2ws);
    loss_kernel<<<1, 256, 0, stream>>>(t2ws, losses);
}